// Round 4
// baseline (2565.916 us; speedup 1.0000x reference)
//
#include <hip/hip_runtime.h>
#include <hip/hip_bf16.h>
#include <math.h>

// B=12, C=64, V=32768, K=32, mid=32, red=16.
// Inputs fp32 (runtime-probed, bf16 fallback path kept). Outputs fp32.
// ws layout (float offsets), total 766400 floats = 2.92 MB:
#define REG_OFF    0
#define ORTHO_OFF  1
#define FLAG_OFF   2          // 1.0 = inputs fp32, 0.0 = bf16
#define MSUM_OFF   4          // [32]
#define RF_OFF     64         // [12][32][64]
#define G_OFF      24640      // [12][64][64]
#define WKW_OFF    73792      // [12][32]
#define MODV_OFF   74176      // [12][32][64]
#define M1T_OFF    98752      // [64 c_in][64 c_out]
#define WKC_OFF    102848     // [12][32][64][27] folded conv weights fp32
#define WS_TOTAL   766400
#define ZERO_FLOATS 73792     // zero: scalars + flag + MSUM + RF + G

#define RF_OUT   0
#define SPAT_OUT 24576
#define ZOUT_OUT 417792
#define SCAL_OUT 25583616

__device__ __forceinline__ float bf2f(unsigned short u) {
  union { unsigned int i; float f; } x; x.i = ((unsigned int)u) << 16; return x.f;
}
__device__ __forceinline__ float ldin(const void* p, size_t i, bool f32) {
  return f32 ? ((const float*)p)[i] : bf2f(((const unsigned short*)p)[i]);
}

// ---------------- input dtype probe ----------------
__global__ void k_probe(const void* __restrict__ Z, float* __restrict__ ws) {
  int t = threadIdx.x;
  const unsigned short* s = (const unsigned short*)Z;
  float mx = 0.f;
  for (int i = t; i < 8192; i += 256) {
    float a = fabsf(bf2f(s[i]));
    if (!(a < 1e30f)) a = 3e38f;   // NaN/Inf count as huge
    mx = fmaxf(mx, a);
  }
  __shared__ float r[256];
  r[t] = mx; __syncthreads();
  for (int o = 128; o > 0; o >>= 1) { if (t < o) r[t] = fmaxf(r[t], r[t + o]); __syncthreads(); }
  if (t == 0) ws[FLAG_OFF] = (r[0] > 1e6f) ? 1.f : 0.f;
}

// ---------------- masks region sizes ----------------
__global__ void k_msum(const void* __restrict__ masks, float* __restrict__ ws) {
  int k = blockIdx.x, t = threadIdx.x;
  bool f32 = ws[FLAG_OFF] > 0.5f;
  float s = 0.f;
  for (int v = t; v < 32768; v += 256) s += ldin(masks, ((size_t)k << 15) + v, f32);
  __shared__ float red[256];
  red[t] = s; __syncthreads();
  for (int off = 128; off > 0; off >>= 1) { if (t < off) red[t] += red[t + off]; __syncthreads(); }
  if (t == 0) ws[MSUM_OFF + k] = red[0];
}

// ---------------- rf partials + channel Gram ----------------
__global__ __launch_bounds__(256) void k_rfgram(const void* __restrict__ Z,
                                                const void* __restrict__ masks,
                                                float* __restrict__ ws) {
  __shared__ float Zt[64][68];
  __shared__ float Mt[64][36];
  int b = blockIdx.y, t = threadIdx.x;
  bool f32 = ws[FLAG_OFF] > 0.5f;
  int ci = t & 15, gj = t >> 4;
  int c0 = ci << 2, c20 = gj << 2, k0 = gj << 1;
  float accG[16], accR[8];
#pragma unroll
  for (int i = 0; i < 16; i++) accG[i] = 0.f;
#pragma unroll
  for (int i = 0; i < 8; i++) accR[i] = 0.f;
  int vs = blockIdx.x << 9;
  for (int t8 = 0; t8 < 8; t8++) {
    int vb = vs + (t8 << 6);
    __syncthreads();
    if (f32) {
      const float* Zf = (const float*)Z;
      const float* Mf = (const float*)masks;
#pragma unroll
      for (int i = 0; i < 8; i++) {
        int idx = (i << 8) + t, c = idx >> 5, v2 = (idx & 31) << 1;
        float2 u = *(const float2*)(Zf + (((size_t)(b << 6) + c) << 15) + vb + v2);
        Zt[v2][c] = u.x; Zt[v2 + 1][c] = u.y;
      }
#pragma unroll
      for (int i = 0; i < 4; i++) {
        int idx = (i << 8) + t, k = idx >> 5, v2 = (idx & 31) << 1;
        float2 u = *(const float2*)(Mf + ((size_t)k << 15) + vb + v2);
        Mt[v2][k] = u.x; Mt[v2 + 1][k] = u.y;
      }
    } else {
      const unsigned short* Zs = (const unsigned short*)Z;
      const unsigned short* Ms = (const unsigned short*)masks;
#pragma unroll
      for (int i = 0; i < 8; i++) {
        int idx = (i << 8) + t, c = idx >> 5, v2 = (idx & 31) << 1;
        unsigned int u = *(const unsigned int*)(Zs + (((size_t)(b << 6) + c) << 15) + vb + v2);
        Zt[v2][c]     = bf2f((unsigned short)(u & 0xffff));
        Zt[v2 + 1][c] = bf2f((unsigned short)(u >> 16));
      }
#pragma unroll
      for (int i = 0; i < 4; i++) {
        int idx = (i << 8) + t, k = idx >> 5, v2 = (idx & 31) << 1;
        unsigned int u = *(const unsigned int*)(Ms + ((size_t)k << 15) + vb + v2);
        Mt[v2][k]     = bf2f((unsigned short)(u & 0xffff));
        Mt[v2 + 1][k] = bf2f((unsigned short)(u >> 16));
      }
    }
    __syncthreads();
    for (int vt = 0; vt < 64; vt++) {
      float4 z1 = *(const float4*)&Zt[vt][c0];
      float4 z2 = *(const float4*)&Zt[vt][c20];
      float2 m2 = *(const float2*)&Mt[vt][k0];
      float z1a[4] = {z1.x, z1.y, z1.z, z1.w};
      float z2a[4] = {z2.x, z2.y, z2.z, z2.w};
      float m2a[2] = {m2.x, m2.y};
#pragma unroll
      for (int i = 0; i < 4; i++) {
#pragma unroll
        for (int j = 0; j < 4; j++) accG[(i << 2) + j] += z1a[i] * z2a[j];
#pragma unroll
        for (int kk = 0; kk < 2; kk++) accR[(i << 1) + kk] += z1a[i] * m2a[kk];
      }
    }
  }
  float* Gd = ws + G_OFF + (b << 12);
  float* Rd = ws + RF_OFF + (b << 11);
#pragma unroll
  for (int i = 0; i < 4; i++) {
#pragma unroll
    for (int j = 0; j < 4; j++) atomicAdd(Gd + ((c0 + i) << 6) + c20 + j, accG[(i << 2) + j]);
#pragma unroll
    for (int kk = 0; kk < 2; kk++) atomicAdd(Rd + ((k0 + kk) << 6) + c0 + i, accR[(i << 1) + kk]);
  }
}

// ---------------- scale rf, emit fp32 rf ----------------
__global__ void k_scale_rf(float* __restrict__ ws, float* __restrict__ out) {
  int i = blockIdx.x * 256 + threadIdx.x;  // < 24576
  int k = (i >> 6) & 31;
  float v = ws[RF_OFF + i] / (ws[MSUM_OFF + k] + 1e-6f);
  ws[RF_OFF + i] = v;
  out[RF_OUT + i] = v;
}

// ---------------- MMD, reg, Wk, mod, M1T ----------------
__global__ void k_small(const int* __restrict__ labels, const void* __restrict__ ages,
                        const void* __restrict__ prior,
                        const void* __restrict__ struct_w, const void* __restrict__ up_w,
                        const void* __restrict__ m_w1, const void* __restrict__ m_b1,
                        const void* __restrict__ m_w2, const void* __restrict__ m_b2,
                        float* __restrict__ ws) {
  __shared__ float x2s[12][32];
  __shared__ float ipk[32][144];
  __shared__ float Dm[32];
  __shared__ float nms[32];
  __shared__ float bases[32];
  __shared__ int labs[12];
  int t = threadIdx.x;
  bool f32 = ws[FLAG_OFF] > 0.5f;
  const float* rf = ws + RF_OFF;
  if (t < 12) labs[t] = labels[t];
  for (int idx = t; idx < 384; idx += 256) {
    const float* r = rf + idx * 64;
    float s = 0.f;
    for (int c = 0; c < 64; c++) s += r[c] * r[c];
    x2s[idx >> 5][idx & 31] = s;
  }
  for (int idx = t; idx < 32 * 144; idx += 256) {
    int k = idx / 144, r2 = idx - k * 144, i = r2 / 12, j = r2 - (r2 / 12) * 12;
    const float* ri = rf + ((i << 5) + k) * 64;
    const float* rj = rf + ((j << 5) + k) * 64;
    float s = 0.f;
    for (int c = 0; c < 64; c++) s += ri[c] * rj[c];
    ipk[k][r2] = s;
  }
  __syncthreads();
  if (t < 32) {
    int k = t;
    const float inv2s2[4] = {1.f / 0.02f, 1.f / 0.5f, 1.f / 2.f, 1.f / 8.f};
    float cnt[3] = {0.f, 0.f, 0.f};
    for (int i = 0; i < 12; i++) cnt[labs[i]] += 1.f;
    float dsum = 0.f;
    for (int s = 0; s < 4; s++) {
      float S[9] = {0,0,0,0,0,0,0,0,0};
      float dg[3] = {0,0,0};
      for (int i = 0; i < 12; i++) {
        int li = labs[i];
        float x2i = x2s[i][k];
        for (int j = 0; j < 12; j++) {
          float d2 = fmaxf(x2i + x2s[j][k] - 2.f * ipk[k][i * 12 + j], 0.f);
          float e = expf(-d2 * inv2s2[s]);
          S[li * 3 + labs[j]] += e;
          if (i == j) dg[li] += e;
        }
      }
      const int pa[3] = {2, 1, 2}, pb[3] = {0, 0, 1};
      for (int p = 0; p < 3; p++) {
        float m = cnt[pa[p]], n = cnt[pb[p]];
        dsum += (S[pa[p] * 3 + pa[p]] - dg[pa[p]]) / (m * (m - 1.f))
              + (S[pb[p] * 3 + pb[p]] - dg[pb[p]]) / (n * (n - 1.f))
              - 2.f * S[pa[p] * 3 + pb[p]] / (m * n);
      }
    }
    Dm[k] = dsum * 0.25f;
  }
  __syncthreads();
  if (t == 0) {
    float mx = 1e-6f;
    for (int k = 0; k < 32; k++) mx = fmaxf(mx, Dm[k]);
    float pw[32];
    float nmax = -1e30f, pmax = -1e30f;
    for (int k = 0; k < 32; k++) {
      nms[k] = fmaxf(Dm[k] / mx, 0.f);
      nmax = fmaxf(nmax, nms[k]);
      pw[k] = (float)ldin(prior, k, f32);
      pmax = fmaxf(pmax, pw[k]);
    }
    float nse = 0.f, pse = 0.f;
    for (int k = 0; k < 32; k++) { nse += expf(nms[k] - nmax); pse += expf(pw[k] - pmax); }
    float lns = logf(nse), lps = logf(pse);
    float reg = 0.f;
    for (int k = 0; k < 32; k++) {
      float lqk = nms[k] - nmax - lns;
      float lpk = pw[k] - pmax - lps;
      reg += 0.5f * (expf(lqk) * (lqk - lpk) + expf(lpk) * (lpk - lqk));
    }
    ws[REG_OFF] = reg / 32.f;
    for (int k = 0; k < 32; k++) bases[k] = 0.7f * pw[k] + 0.3f * nms[k];
  }
  __syncthreads();
  if (t < 12) {
    float x = 0.1f * (ldin(ages, t, f32) - 50.f);
    float af = 1.f + fmaxf(x, 0.f) + log1pf(expf(-fabsf(x)));
    float w[32];
    float mx = -1e30f;
    for (int k = 0; k < 32; k++) {
      float v = fminf(fmaxf(bases[k] * af, 0.f), 2.f);
      w[k] = v; mx = fmaxf(mx, v);
    }
    float se = 0.f;
    for (int k = 0; k < 32; k++) se += expf(w[k] - mx);
    for (int k = 0; k < 32; k++) ws[WKW_OFF + (t << 5) + k] = expf(w[k] - mx) / se;
  }
  for (int idx = t; idx < 384; idx += 256) {   // mod[b,k,c]
    const float* r = rf + idx * 64;
    float h[16];
    for (int rr = 0; rr < 16; rr++) {
      float s = ldin(m_b1, rr, f32);
      for (int c = 0; c < 64; c++) s += r[c] * ldin(m_w1, rr * 64 + c, f32);
      h[rr] = fmaxf(s, 0.f);
    }
    for (int c = 0; c < 64; c++) {
      float s = ldin(m_b2, c, f32);
      for (int rr = 0; rr < 16; rr++) s += h[rr] * ldin(m_w2, c * 16 + rr, f32);
      ws[MODV_OFF + (idx << 6) + c] = fmaxf(s, 0.f) + log1pf(expf(-fabsf(s)));
    }
  }
  for (int idx = t; idx < 4096; idx += 256) {  // M1T[c_in][c_out]
    int cin = idx >> 6, co = idx & 63;
    float s = 0.f;
    for (int j = 0; j < 32; j++) s += ldin(up_w, co * 32 + j, f32) * ldin(struct_w, j * 64 + cin, f32);
    ws[M1T_OFF + idx] = s;
  }
}

// ---------------- ortho from Gram ----------------
__global__ void k_ortho(const void* __restrict__ sw, const void* __restrict__ nw,
                        float* __restrict__ ws) {
  int b = blockIdx.x >> 5, o = blockIdx.x & 31, c = threadIdx.x;
  bool f32 = ws[FLAG_OFF] > 0.5f;
  const float* Gb = ws + G_OFF + (b << 12);
  float ts = 0.f, tn = 0.f;
  for (int c2 = 0; c2 < 64; c2++) {
    float g = Gb[(c << 6) + c2];
    ts += g * ldin(sw, (o << 6) + c2, f32);
    tn += g * ldin(nw, (o << 6) + c2, f32);
  }
  float swc = ldin(sw, (o << 6) + c, f32);
  float nwc = ldin(nw, (o << 6) + c, f32);
  float ds = swc * tn, ss = swc * ts, nn = nwc * tn;
  for (int off = 32; off > 0; off >>= 1) {
    ds += __shfl_down(ds, off);
    ss += __shfl_down(ss, off);
    nn += __shfl_down(nn, off);
  }
  if (c == 0) {
    ss = fmaxf(ss, 0.f); nn = fmaxf(nn, 0.f);
    float cosv = ds / (fmaxf(sqrtf(ss), 1e-8f) * fmaxf(sqrtf(nn), 1e-8f));
    atomicAdd(ws + ORTHO_OFF, fabsf(cosv) * (1.f / 384.f));
  }
}

// ---------------- folded conv weights wk[b,k,o,d] ----------------
__global__ void k_wk(const void* __restrict__ rw, float* __restrict__ ws) {
  int bk = blockIdx.x;  // b*32+k
  int t = threadIdx.x;
  bool f32 = ws[FLAG_OFF] > 0.5f;
  __shared__ float rl[64];
  if (t < 64) rl[t] = ws[RF_OFF + (bk << 6) + t];
  __syncthreads();
  float* dst = ws + WKC_OFF + (size_t)bk * 1728;
  for (int idx = t; idx < 1728; idx += 256) {
    int o = idx / 27, d = idx - o * 27;
    float s = 0.f;
    for (int c = 0; c < 64; c++) s += rl[c] * ldin(rw, (size_t)o * 1728 + c * 27 + d, f32);
    dst[idx] = s;
  }
}

// ---------------- spatial output (fp32) ----------------
__global__ void k_spatial(const void* __restrict__ masks, const float* __restrict__ ws,
                          float* __restrict__ out) {
  int b = blockIdx.y, t = threadIdx.x;
  bool f32 = ws[FLAG_OFF] > 0.5f;
  __shared__ float wl[32];
  if (t < 32) wl[t] = ws[WKW_OFF + (b << 5) + t];
  __syncthreads();
  int v0 = (blockIdx.x << 11) + (t << 3);
  float s[8] = {0, 0, 0, 0, 0, 0, 0, 0};
  for (int k = 0; k < 32; k++) {
    float wkv = wl[k];
    float mv[8];
    if (f32) {
      const float* Mf = (const float*)masks + ((size_t)k << 15) + v0;
      float4 a = *(const float4*)Mf, bb = *(const float4*)(Mf + 4);
      mv[0]=a.x; mv[1]=a.y; mv[2]=a.z; mv[3]=a.w; mv[4]=bb.x; mv[5]=bb.y; mv[6]=bb.z; mv[7]=bb.w;
    } else {
      uint4 u = *(const uint4*)((const unsigned short*)masks + ((size_t)k << 15) + v0);
      mv[0]=bf2f((unsigned short)(u.x & 0xffff)); mv[1]=bf2f((unsigned short)(u.x >> 16));
      mv[2]=bf2f((unsigned short)(u.y & 0xffff)); mv[3]=bf2f((unsigned short)(u.y >> 16));
      mv[4]=bf2f((unsigned short)(u.z & 0xffff)); mv[5]=bf2f((unsigned short)(u.z >> 16));
      mv[6]=bf2f((unsigned short)(u.w & 0xffff)); mv[7]=bf2f((unsigned short)(u.w >> 16));
    }
#pragma unroll
    for (int j = 0; j < 8; j++) s[j] += wkv * mv[j];
  }
#pragma unroll
  for (int j = 0; j < 8; j++) out[SPAT_OUT + (b << 15) + v0 + j] = s[j];
}

// ---------------- fused final (fp32 out) ----------------
__global__ __launch_bounds__(256) void k_final(const void* __restrict__ Z,
                                               const void* __restrict__ masks,
                                               const float* __restrict__ ws,
                                               float* __restrict__ out) {
  __shared__ unsigned short MH[32][608];  // mask halo 6x10x10, bf16 bits (masks 0/1: exact)
  __shared__ float wl[32];
  int b = blockIdx.y, tile = blockIdx.x, t = threadIdx.x;
  bool f32 = ws[FLAG_OFF] > 0.5f;
  int d0 = (tile >> 4) << 2, h0 = ((tile >> 2) & 3) << 3, w0 = (tile & 3) << 3;
  for (int i = t; i < 32 * 600; i += 256) {
    int k = i / 600, r = i - k * 600;
    int hd = r / 100, rr = r - hd * 100, hh = rr / 10, hw = rr - hh * 10;
    int gd = d0 - 1 + hd, gh = h0 - 1 + hh, gw = w0 - 1 + hw;
    unsigned short val = 0;
    if ((unsigned)gd < 32u && (unsigned)gh < 32u && (unsigned)gw < 32u) {
      float mv = ldin(masks, ((size_t)k << 15) + (gd << 10) + (gh << 5) + gw, f32);
      val = (unsigned short)(__float_as_uint(mv) >> 16);   // exact for 0.0/1.0
    }
    MH[k][r] = val;
  }
  if (t < 32) wl[t] = ws[WKW_OFF + (b << 5) + t];
  __syncthreads();
  int dz = t >> 6, hy = (t >> 3) & 7, wx = t & 7;
  int v = ((d0 + dz) << 10) + ((h0 + hy) << 5) + (w0 + wx);
  int hbase = dz * 100 + hy * 10 + wx;
  float cen[32];
  float sp = 0.f;
#pragma unroll
  for (int k = 0; k < 32; k++) {
    float cm = bf2f(MH[k][hbase + 111]);
    cen[k] = cm;
    sp += wl[k] * cm;
  }
  const float* wkb = ws + WKC_OFF + (size_t)b * (32 * 1728);
  const float* modb = ws + MODV_OFF + (b << 11);
  const float* m1t = ws + M1T_OFF;
  float acc[64];
#pragma unroll
  for (int o = 0; o < 64; o++) acc[o] = 0.f;
#pragma unroll 1
  for (int k = 0; k < 32; k++) {
    float m[27];
#pragma unroll
    for (int a = 0; a < 3; a++)
#pragma unroll
      for (int bb = 0; bb < 3; bb++)
#pragma unroll
        for (int cc = 0; cc < 3; cc++)
          m[a * 9 + bb * 3 + cc] = bf2f(MH[k][hbase + a * 100 + bb * 10 + cc]);
    const float* wkk = wkb + k * 1728;
#pragma unroll
    for (int o = 0; o < 64; o++) {
      const float* wo = wkk + o * 27;   // wave-uniform -> scalar loads
      float s = 0.f;
#pragma unroll
      for (int d = 0; d < 27; d++) s += wo[d] * m[d];
      acc[o] += s;
    }
  }
#pragma unroll 1
  for (int o = 0; o < 64; o++) {
    float mm = 0.f;
#pragma unroll
    for (int k = 0; k < 32; k++) mm += modb[(k << 6) + o] * cen[k];
    acc[o] *= 0.1f * sp * mm;
  }
#pragma unroll 1
  for (int c = 0; c < 64; c++) {
    float zv = ldin(Z, (((size_t)(b << 6) + c) << 15) + v, f32);
    const float* mrow = m1t + (c << 6);
#pragma unroll
    for (int o = 0; o < 64; o++) acc[o] += mrow[o] * zv;
  }
  size_t obase = (size_t)ZOUT_OUT + (((size_t)(b << 6)) << 15) + v;
#pragma unroll
  for (int o = 0; o < 64; o++) out[obase + ((size_t)o << 15)] = acc[o];
  if ((t | tile | b) == 0) out[SCAL_OUT] = ws[REG_OFF] + ws[ORTHO_OFF];
}

extern "C" void kernel_launch(void* const* d_in, const int* in_sizes, int n_in,
                              void* d_out, int out_size, void* d_ws, size_t ws_size,
                              hipStream_t stream) {
  (void)in_sizes; (void)n_in; (void)out_size; (void)ws_size;
  const void* Z        = d_in[0];
  const void* masks    = d_in[1];
  const int*  labels   = (const int*)d_in[2];
  const void* ages     = d_in[3];
  const void* prior    = d_in[4];
  const void* struct_w = d_in[5];
  const void* noise_w  = d_in[6];
  const void* up_w     = d_in[7];
  const void* region_w = d_in[8];
  const void* m_w1     = d_in[9];
  const void* m_b1     = d_in[10];
  const void* m_w2     = d_in[11];
  const void* m_b2     = d_in[12];
  float* ws = (float*)d_ws;
  float* out = (float*)d_out;

  hipMemsetAsync(d_ws, 0, (size_t)ZERO_FLOATS * 4, stream);
  k_probe<<<1, 256, 0, stream>>>(Z, ws);
  k_msum<<<32, 256, 0, stream>>>(masks, ws);
  k_rfgram<<<dim3(64, 12), 256, 0, stream>>>(Z, masks, ws);
  k_scale_rf<<<96, 256, 0, stream>>>(ws, out);
  k_small<<<1, 256, 0, stream>>>(labels, ages, prior, struct_w, up_w, m_w1, m_b1, m_w2, m_b2, ws);
  k_ortho<<<384, 64, 0, stream>>>(struct_w, noise_w, ws);
  k_wk<<<384, 256, 0, stream>>>(region_w, ws);
  k_spatial<<<dim3(16, 12), 256, 0, stream>>>(masks, ws, out);
  k_final<<<dim3(128, 12), 256, 0, stream>>>(Z, masks, ws, out);
}